// Round 4
// baseline (850.005 us; speedup 1.0000x reference)
//
#include <hip/hip_runtime.h>
#include <hip/hip_bf16.h>
#include <math.h>

// Swin block: LN1 -> shift+window -> QKV -> MFMA attn -> proj(+reverse+res)
//             -> LN2 -> FUSED MLP (fc1+GELU+fc2+res, h never touches HBM)
// R9: fused_mlp v7 — v4's 512-thread/128-row structure, spill fixed.
//     Diagnosis chain: v3 (268us) / v6-pipeline (306us) are bound by per-CU
//     weight staging (each 64-row block re-reads the full 1MB of fc1+fc2
//     weights: 6MB/CU at ~10B/cyc ~= the whole runtime). The fix is M=128
//     per block (halves staged bytes/CU), which v4 implemented correctly but
//     launch_bounds(512,4) imposed a 128-reg/wave cap -> scratch spill
//     (+430MB HBM). v7 = v4 with __launch_bounds__(512,2): compiler
//     allocates ~92 VGPR naturally -> 4 waves/SIMD, 2 blocks/CU, no spill.

typedef __bf16 bf16_t;
typedef __bf16 bf16x4 __attribute__((ext_vector_type(4)));
typedef __bf16 bf16x8 __attribute__((ext_vector_type(8)));
typedef float f32x4 __attribute__((ext_vector_type(4)));

#define AS1 __attribute__((address_space(1)))
#define AS3 __attribute__((address_space(3)))

__device__ __forceinline__ void gload_lds16(const bf16_t* g, bf16_t* l) {
  __builtin_amdgcn_global_load_lds((AS1 void*)g, (AS3 void*)l, 16, 0, 0);
}

// ---------------- weight transpose + cast (3 K=256 weights in one grid) ---
__global__ void transpose_cast3(const float* __restrict__ qkv_w,
                                const float* __restrict__ proj_w,
                                const float* __restrict__ fc1_w,
                                bf16_t* __restrict__ qkvWt,
                                bf16_t* __restrict__ projWt,
                                bf16_t* __restrict__ fc1Wt) {
  int idx = blockIdx.x * 256 + threadIdx.x;
  const float* w;
  bf16_t* wt;
  int N;
  if (blockIdx.y == 0) { w = qkv_w; wt = qkvWt; N = 768; }
  else if (blockIdx.y == 1) { w = proj_w; wt = projWt; N = 256; }
  else { w = fc1_w; wt = fc1Wt; N = 1024; }
  if (idx < N * 256) {
    int n = idx >> 8, k = idx & 255;
    wt[idx] = (bf16_t)w[(size_t)k * N + n];
  }
}

__global__ void transpose_cast(const float* __restrict__ w, bf16_t* __restrict__ wt,
                               int K, int N) {
  int idx = blockIdx.x * 256 + threadIdx.x;
  if (idx < N * K) {
    int n = idx / K, k = idx - n * K;
    wt[idx] = (bf16_t)w[(size_t)k * N + n];
  }
}

// ---------------- bias+mask table: bm[type][head][64][64] fp32 -----------
__global__ void build_bm(const float* __restrict__ rpb, float* __restrict__ bm) {
  int t = blockIdx.x, h = blockIdx.y;
  int wr = (t & 2) ? 7 : 0, wc = (t & 1) ? 7 : 0;
  for (int e = threadIdx.x; e < 4096; e += 256) {
    int r = e >> 6, c = e & 63;
    float v;
    if (c >= 49) {
      v = -30000.f;
    } else if (r >= 49) {
      v = 0.f;
    } else {
      int r1 = r / 7, c1 = r - r1 * 7;
      int r2 = c / 7, c2 = c - r2 * 7;
      v = rpb[((r1 - r2 + 6) * 13 + (c1 - c2 + 6)) * 8 + h];
      int hp = wr * 7 + r1, wp = wc * 7 + c1;
      int hq = wr * 7 + r2, wq = wc * 7 + c2;
      int ri = (hp < 49 ? 0 : (hp < 53 ? 1 : 2)) * 3 + (wp < 49 ? 0 : (wp < 53 ? 1 : 2));
      int rj = (hq < 49 ? 0 : (hq < 53 ? 1 : 2)) * 3 + (wq < 49 ? 0 : (wq < 53 ? 1 : 2));
      if (ri != rj) v -= 100.f;
    }
    bm[((size_t)(t * 8 + h) * 64 + r) * 64 + c] = v;
  }
}

// ---------------- LayerNorm (+ optional shift/window gather) -> bf16 ------
__global__ __launch_bounds__(256)
void ln_cast(const float* __restrict__ src, const float* __restrict__ gamma,
             const float* __restrict__ beta, bf16_t* __restrict__ dst, int windowed) {
  int row = blockIdx.x * 4 + (threadIdx.x >> 6);
  int lane = threadIdx.x & 63;
  size_t srow;
  if (windowed) {
    int w = row / 49, t = row - w * 49;
    int img = w >> 6, wi = w & 63;
    int wr = wi >> 3, wc = wi & 7;
    int rr = t / 7, cc = t - rr * 7;
    int h = wr * 7 + rr + 3; if (h >= 56) h -= 56;
    int ww = wc * 7 + cc + 3; if (ww >= 56) ww -= 56;
    srow = (size_t)img * 3136 + h * 56 + ww;
  } else {
    srow = row;
  }
  float4 v = *(const float4*)(src + srow * 256 + lane * 4);
  float s = v.x + v.y + v.z + v.w;
  float s2 = v.x * v.x + v.y * v.y + v.z * v.z + v.w * v.w;
#pragma unroll
  for (int off = 32; off > 0; off >>= 1) {
    s += __shfl_xor(s, off);
    s2 += __shfl_xor(s2, off);
  }
  float mu = s * (1.0f / 256.0f);
  float rs = rsqrtf(s2 * (1.0f / 256.0f) - mu * mu + 1e-5f);
  float4 g = *(const float4*)(gamma + lane * 4);
  float4 b = *(const float4*)(beta + lane * 4);
  bf16x4 o;
  o[0] = (bf16_t)((v.x - mu) * rs * g.x + b.x);
  o[1] = (bf16_t)((v.y - mu) * rs * g.y + b.y);
  o[2] = (bf16_t)((v.z - mu) * rs * g.z + b.z);
  o[3] = (bf16_t)((v.w - mu) * rs * g.w + b.w);
  *(bf16x4*)(dst + (size_t)row * 256 + lane * 4) = o;
}

// ---------------- GEMM: C[M,N] = A[M,K] * Bt[N,K]^T -----------------------
// 1-D grid, n-major within m: consecutive blocks share the A-tile (L2 reuse).
// MODE 0: +bias -> bf16 (QKV)   MODE 3: +bias+Res[map(row)] -> fp32 (proj)
template <int MODE>
__global__ __launch_bounds__(256)
void gemm_bt(const bf16_t* __restrict__ A, const bf16_t* __restrict__ Bt,
             const float* __restrict__ bias,
             bf16_t* Cbf, float* Cf, const float* Res,
             int M, int N, int K, int nblk) {
  __shared__ __align__(16) bf16_t As[128 * 32];
  __shared__ __align__(16) bf16_t Bs[128 * 32];
  const int tid = threadIdx.x;
  const int lane = tid & 63;
  const int wave = tid >> 6;
  const int wm = wave & 1, wn = wave >> 1;
  const int bid = blockIdx.x;
  const int m_idx = bid / nblk;
  const int n_idx = bid - m_idx * nblk;
  const int m0 = m_idx * 128;
  const int n0 = n_idx * 128;

  f32x4 acc[4][4];
#pragma unroll
  for (int i = 0; i < 4; i++)
#pragma unroll
    for (int j = 0; j < 4; j++) acc[i][j] = f32x4{0.f, 0.f, 0.f, 0.f};

  const bf16_t* Ag = A + (size_t)m0 * K;
  const bf16_t* Bg = Bt + (size_t)n0 * K;
  const int lr = lane & 15;
  const int kq = (lane >> 4) * 8;

  for (int k0 = 0; k0 < K; k0 += 32) {
#pragma unroll
    for (int it = 0; it < 2; it++) {
      int slot = it * 256 + tid;
      int row = slot >> 2;
      int ko = (slot & 3) << 3;
      bf16_t* ldsA = As + (it * 256 + wave * 64) * 8;
      bf16_t* ldsB = Bs + (it * 256 + wave * 64) * 8;
      gload_lds16(Ag + (size_t)row * K + k0 + ko, ldsA);
      gload_lds16(Bg + (size_t)row * K + k0 + ko, ldsB);
    }
    __syncthreads();
    bf16x8 af[4], bfr[4];
#pragma unroll
    for (int i = 0; i < 4; i++) {
      af[i]  = *(const bf16x8*)(As + (wm * 64 + i * 16 + lr) * 32 + kq);
      bfr[i] = *(const bf16x8*)(Bs + (wn * 64 + i * 16 + lr) * 32 + kq);
    }
#pragma unroll
    for (int i = 0; i < 4; i++)
#pragma unroll
      for (int j = 0; j < 4; j++)
        acc[i][j] = __builtin_amdgcn_mfma_f32_16x16x32_bf16(af[i], bfr[j], acc[i][j], 0, 0, 0);
    __syncthreads();
  }

  const int quad = lane >> 4;
#pragma unroll
  for (int i = 0; i < 4; i++) {
    int rbase = m0 + wm * 64 + i * 16 + quad * 4;
#pragma unroll
    for (int j = 0; j < 4; j++) {
      int col = n0 + wn * 64 + j * 16 + lr;
      float bi = bias[col];
#pragma unroll
      for (int r = 0; r < 4; r++) {
        int row = rbase + r;
        float v = acc[i][j][r] + bi;
        if (MODE == 0) {
          Cbf[(size_t)row * N + col] = (bf16_t)v;
        } else {
          int w = row / 49, t = row - w * 49;
          int img = w >> 6, wi = w & 63;
          int wr = wi >> 3, wc = wi & 7;
          int rr = t / 7, cc = t - rr * 7;
          int h = wr * 7 + rr + 3; if (h >= 56) h -= 56;
          int ww2 = wc * 7 + cc + 3; if (ww2 >= 56) ww2 -= 56;
          size_t idx = ((size_t)img * 3136 + h * 56 + ww2) * 256 + col;
          Cf[idx] = v + Res[idx];
        }
      }
    }
  }
}

// ---------------- MFMA attention: one block (4 waves) per (window, head) --
__global__ __launch_bounds__(256)
void attn_mfma(const bf16_t* __restrict__ qkv, const float* __restrict__ bm,
               bf16_t* __restrict__ o) {
  __shared__ __align__(16) bf16_t Ps[64 * 72];
  __shared__ __align__(16) bf16_t Vt[32 * 72];
  const int w = blockIdx.x, h = blockIdx.y;
  const int tid = threadIdx.x;
  const int lane = tid & 63, wv = tid >> 6;
  const int lr = lane & 15, quad = lane >> 4;
  const int wi = w & 63;
  const int mtype = (((wi >> 3) == 7) ? 2 : 0) | (((wi & 7) == 7) ? 1 : 0);
  const bf16_t* base = qkv + (size_t)w * 49 * 768 + h * 32;

  bf16x8 zero8;
#pragma unroll
  for (int z = 0; z < 8; z++) zero8[z] = (bf16_t)0.f;

  {
    int tok = tid >> 2, d8 = (tid & 3) * 8;
    bf16x8 v8 = zero8;
    if (tok < 49) v8 = *(const bf16x8*)(base + (size_t)tok * 768 + 512 + d8);
#pragma unroll
    for (int z = 0; z < 8; z++) Vt[(d8 + z) * 72 + tok] = v8[z];
  }
  __syncthreads();

  const int mrow = 16 * wv + lr;
  bf16x8 aq = zero8;
  if (mrow < 49) aq = *(const bf16x8*)(base + (size_t)mrow * 768 + quad * 8);
  f32x4 s[4];
#pragma unroll
  for (int j = 0; j < 4; j++) {
    int nrow = 16 * j + lr;
    bf16x8 bk = zero8;
    if (nrow < 49) bk = *(const bf16x8*)(base + (size_t)nrow * 768 + 256 + quad * 8);
    s[j] = __builtin_amdgcn_mfma_f32_16x16x32_bf16(aq, bk, f32x4{0.f, 0.f, 0.f, 0.f}, 0, 0, 0);
  }

  const float* bmb = bm + ((size_t)(mtype * 8 + h) * 64 + 16 * wv) * 64;
  float inv[4];
#pragma unroll
  for (int reg = 0; reg < 4; reg++) {
    int rl = quad * 4 + reg;
    float v0[4];
    float mx = -1e30f;
#pragma unroll
    for (int j = 0; j < 4; j++) {
      float v = s[j][reg] * 0.17677669529663689f + bmb[rl * 64 + 16 * j + lr];
      v0[j] = v;
      mx = fmaxf(mx, v);
    }
#pragma unroll
    for (int off = 8; off > 0; off >>= 1) mx = fmaxf(mx, __shfl_xor(mx, off));
    float sum = 0.f;
#pragma unroll
    for (int j = 0; j < 4; j++) {
      float e = __expf(v0[j] - mx);
      v0[j] = e;
      sum += e;
    }
#pragma unroll
    for (int off = 8; off > 0; off >>= 1) sum += __shfl_xor(sum, off);
    inv[reg] = 1.0f / sum;
#pragma unroll
    for (int j = 0; j < 4; j++)
      Ps[(16 * wv + rl) * 72 + 16 * j + lr] = (bf16_t)v0[j];
  }

  f32x4 oacc[2];
  oacc[0] = f32x4{0.f, 0.f, 0.f, 0.f};
  oacc[1] = f32x4{0.f, 0.f, 0.f, 0.f};
#pragma unroll
  for (int kk = 0; kk < 2; kk++) {
    bf16x8 ap = *(const bf16x8*)(Ps + (16 * wv + lr) * 72 + kk * 32 + quad * 8);
#pragma unroll
    for (int n = 0; n < 2; n++) {
      bf16x8 bv = *(const bf16x8*)(Vt + (16 * n + lr) * 72 + kk * 32 + quad * 8);
      oacc[n] = __builtin_amdgcn_mfma_f32_16x16x32_bf16(ap, bv, oacc[n], 0, 0, 0);
    }
  }
#pragma unroll
  for (int n = 0; n < 2; n++) {
#pragma unroll
    for (int reg = 0; reg < 4; reg++) {
      int row = 16 * wv + quad * 4 + reg;
      if (row < 49) {
        int d = 16 * n + lr;
        o[((size_t)w * 49 + row) * 256 + h * 32 + d] = (bf16_t)(oacc[n][reg] * inv[reg]);
      }
    }
  }
}

// ---------------- FUSED MLP v7: out += fc2(gelu(fc1(y2))) -----------------
// 512 threads = 8 waves; wave owns rows [m0+16w, m0+16w+16), M-tile = 128.
// A-frags (y2, K=256) resident in 32 VGPRs, loaded once. Per hidden chunk hc
// (128): phase A (2 k-steps of 128, Ws 32KB staged, 32 MFMA each) -> GELU ->
// wave-local Hs strip -> phase B (2 k-steps of 64 over hidden, Ws 32KB,
// 32 MFMA each). Barriers only guard Ws. Vs v3: same staging bytes per block
// but 2x MFMA per barrier-drain, half the blocks (half weight traffic/CU).
// __launch_bounds__(512,2): do NOT cap regs at 128 (v4's (512,4) did ->
// spill, +430MB HBM scratch). Compiler allocates ~92 -> 4 waves/SIMD
// anyway -> 2 blocks/CU (67.5KB LDS) = 16 waves/CU.
__global__ __launch_bounds__(512, 2)
void fused_mlp(const bf16_t* __restrict__ y2, const bf16_t* __restrict__ W1t,
               const float* __restrict__ b1, const bf16_t* __restrict__ W2t,
               const float* __restrict__ b2, float* __restrict__ out) {
  __shared__ __align__(16) bf16_t Ws[16384];        // 32 KB weight staging
  __shared__ __align__(16) bf16_t Hs[8 * 16 * 136]; // 34.8 KB, per-wave strips
  const int tid = threadIdx.x;
  const int lane = tid & 63, wave = tid >> 6;       // wave in [0,8)
  const int lr = lane & 15, quad = lane >> 4;
  const int m0 = blockIdx.x * 128;
  bf16_t* HsW = Hs + wave * (16 * 136);

  // resident A-frags: row = m0+16*wave+lr, k = ks*128 + kk*32 + quad*8
  const bf16_t* Arow = y2 + (size_t)(m0 + 16 * wave + lr) * 256;
  bf16x8 aF[2][4];
#pragma unroll
  for (int ks = 0; ks < 2; ks++)
#pragma unroll
    for (int kk = 0; kk < 4; kk++)
      aF[ks][kk] = *(const bf16x8*)(Arow + ks * 128 + kk * 32 + quad * 8);

  f32x4 acc2[16];
#pragma unroll
  for (int n = 0; n < 16; n++) acc2[n] = f32x4{0.f, 0.f, 0.f, 0.f};

  for (int hc = 0; hc < 8; hc++) {
    // ---- phase A: H[16w..+16, 128] = y2 @ W1t[hc*128..+128]^T
    f32x4 acc1[8];
#pragma unroll
    for (int j = 0; j < 8; j++) acc1[j] = f32x4{0.f, 0.f, 0.f, 0.f};

    for (int ks = 0; ks < 2; ks++) {
      __syncthreads();                       // all waves done reading Ws
#pragma unroll
      for (int kk = 0; kk < 4; kk++) {       // stage 128 rows x 32 k (8KB/kk)
        int row = wave * 16 + (lane >> 2);   // 1 load/thread/kk
        int k8 = lane & 3;
        const bf16_t* src = W1t + (size_t)(hc * 128 + row) * 256
                            + ks * 128 + kk * 32 + k8 * 8;
        gload_lds16(src, Ws + kk * 4096 + (wave * 16) * 32);
      }
      __syncthreads();                       // staged data visible
#pragma unroll
      for (int kk = 0; kk < 4; kk++) {
#pragma unroll
        for (int j = 0; j < 8; j++) {
          bf16x8 b = *(const bf16x8*)(Ws + kk * 4096 + (16 * j + lr) * 32 + quad * 8);
          acc1[j] = __builtin_amdgcn_mfma_f32_16x16x32_bf16(aF[ks][kk], b, acc1[j], 0, 0, 0);
        }
      }
    }
    // GELU (exact, erf) -> wave-local Hs strip [16 rows][128 cols] stride 136
#pragma unroll
    for (int j = 0; j < 8; j++) {
      float bias1 = b1[hc * 128 + 16 * j + lr];
#pragma unroll
      for (int reg = 0; reg < 4; reg++) {
        float v = acc1[j][reg] + bias1;
        v = 0.5f * v * (1.0f + erff(v * 0.70710678118654752f));
        HsW[(4 * quad + reg) * 136 + 16 * j + lr] = (bf16_t)v;
      }
    }
    // ---- phase B: acc2 += H @ W2t[:, hc*128..+128]^T
    for (int ks2 = 0; ks2 < 2; ks2++) {
      __syncthreads();                       // Ws reads done (Hs is wave-local)
#pragma unroll
      for (int kk = 0; kk < 2; kk++) {       // stage 256 rows x 32 k (16KB/kk)
#pragma unroll
        for (int it = 0; it < 2; it++) {     // 1 load/thread/(kk,it)
          int row = it * 128 + wave * 16 + (lane >> 2);
          int k8 = lane & 3;
          const bf16_t* src = W2t + (size_t)row * 1024
                              + hc * 128 + ks2 * 64 + kk * 32 + k8 * 8;
          gload_lds16(src, Ws + kk * 8192 + (it * 128 + wave * 16) * 32);
        }
      }
      __syncthreads();
#pragma unroll
      for (int kk = 0; kk < 2; kk++) {
        bf16x8 ah = *(const bf16x8*)(HsW + lr * 136 + ks2 * 64 + kk * 32 + quad * 8);
#pragma unroll
        for (int n = 0; n < 16; n++) {
          bf16x8 bw = *(const bf16x8*)(Ws + kk * 8192 + (16 * n + lr) * 32 + quad * 8);
          acc2[n] = __builtin_amdgcn_mfma_f32_16x16x32_bf16(ah, bw, acc2[n], 0, 0, 0);
        }
      }
    }
  }

  // epilogue: out += acc2 + b2 (rows m0 + 16*wave + 4*quad + reg, cols 16n+lr)
#pragma unroll
  for (int n = 0; n < 16; n++) {
    int col = 16 * n + lr;
    float bi = b2[col];
#pragma unroll
    for (int reg = 0; reg < 4; reg++) {
      int row = m0 + 16 * wave + 4 * quad + reg;
      size_t idx = (size_t)row * 256 + col;
      out[idx] = acc2[n][reg] + bi + out[idx];
    }
  }
}

// ---------------- launcher ------------------------------------------------
extern "C" void kernel_launch(void* const* d_in, const int* in_sizes, int n_in,
                              void* d_out, int out_size, void* d_ws, size_t ws_size,
                              hipStream_t stream) {
  const float* x      = (const float*)d_in[0];
  const float* g1     = (const float*)d_in[1];
  const float* b1     = (const float*)d_in[2];
  const float* qkv_w  = (const float*)d_in[3];
  const float* qkv_b  = (const float*)d_in[4];
  const float* proj_w = (const float*)d_in[5];
  const float* proj_b = (const float*)d_in[6];
  const float* rpb    = (const float*)d_in[7];
  const float* g2     = (const float*)d_in[8];
  const float* b2     = (const float*)d_in[9];
  const float* fc1_w  = (const float*)d_in[10];
  const float* fc1_b  = (const float*)d_in[11];
  const float* fc2_w  = (const float*)d_in[12];
  const float* fc2_b  = (const float*)d_in[13];
  float* out = (float*)d_out;
  char* ws = (char*)d_ws;

  bf16_t* xw   = (bf16_t*)ws;                  // [0,51.4M) LN1 out, later y2
  bf16_t* qkv  = (bf16_t*)(ws + 51380224);     // [51.4,205.5M)
  bf16_t* ow   = (bf16_t*)(ws + 205520896);    // [205.5,256.9M)
  bf16_t* y2   = xw;
  bf16_t* qkvWt  = (bf16_t*)(ws + 256901120);
  bf16_t* projWt = qkvWt + 768 * 256;
  bf16_t* fc1Wt  = projWt + 256 * 256;
  bf16_t* fc2Wt  = fc1Wt + 1024 * 256;         // 512 KB, time-shared with bm
  float*  bm     = (float*)fc2Wt;

  transpose_cast3<<<dim3(1024, 3), 256, 0, stream>>>(qkv_w, proj_w, fc1_w,
                                                     qkvWt, projWt, fc1Wt);
  build_bm<<<dim3(4, 8), 256, 0, stream>>>(rpb, bm);

  ln_cast<<<25088, 256, 0, stream>>>(x, g1, b1, xw, 1);
  gemm_bt<0><<<784 * 6, 256, 0, stream>>>(xw, qkvWt, qkv_b, qkv, nullptr, nullptr,
                                          100352, 768, 256, 6);
  attn_mfma<<<dim3(2048, 8), 256, 0, stream>>>(qkv, bm, ow);
  // bm dead -> transpose fc2 into its region
  transpose_cast<<<(256 * 1024 + 255) / 256, 256, 0, stream>>>(fc2_w, fc2Wt, 1024, 256);
  gemm_bt<3><<<784 * 2, 256, 0, stream>>>(ow, projWt, proj_b, nullptr, out, x,
                                          100352, 256, 256, 2);
  ln_cast<<<25088, 256, 0, stream>>>(out, g2, b2, y2, 0);
  fused_mlp<<<784, 512, 0, stream>>>(y2, fc1Wt, fc1_b, fc2Wt, fc2_b, out);
}

// Round 5
// 794.585 us; speedup vs baseline: 1.0697x; 1.0697x over previous
//
#include <hip/hip_runtime.h>
#include <hip/hip_bf16.h>
#include <math.h>

// Swin block: LN1 -> shift+window -> QKV -> MFMA attn -> proj(+reverse+res)
//             -> LN2 -> FUSED MLP (fc1+GELU+fc2+res, h never touches HBM)
// R10: fused_mlp v8 — latency-bound diagnosis (perf tracks blocks/CU:
//     3->268us, 2->306/347us; all pipes <23%). Keep v3's 3 blocks/CU AND
//     add pipelining: Ws split into 2x16KB ping-pong (total LDS still 49KB),
//     T3 minimum-2-phase schedule: sync -> issue STAGE(s+1) into buf^1 ->
//     compute(s) from buf^0 -> sync. The __syncthreads vmcnt(0) drain now
//     waits on a DMA issued a whole compute-phase earlier (hidden), not
//     immediately before (v3). Staging+swizzle math verbatim v6 (proven).
//     + T5 setprio around MFMA, GELU placed to overlap B0-stage DMA.

typedef __bf16 bf16_t;
typedef __bf16 bf16x4 __attribute__((ext_vector_type(4)));
typedef __bf16 bf16x8 __attribute__((ext_vector_type(8)));
typedef float f32x4 __attribute__((ext_vector_type(4)));

#define AS1 __attribute__((address_space(1)))
#define AS3 __attribute__((address_space(3)))

__device__ __forceinline__ void gload_lds16(const bf16_t* g, bf16_t* l) {
  __builtin_amdgcn_global_load_lds((AS1 void*)g, (AS3 void*)l, 16, 0, 0);
}

// ---------------- weight transpose + cast (3 K=256 weights in one grid) ---
__global__ void transpose_cast3(const float* __restrict__ qkv_w,
                                const float* __restrict__ proj_w,
                                const float* __restrict__ fc1_w,
                                bf16_t* __restrict__ qkvWt,
                                bf16_t* __restrict__ projWt,
                                bf16_t* __restrict__ fc1Wt) {
  int idx = blockIdx.x * 256 + threadIdx.x;
  const float* w;
  bf16_t* wt;
  int N;
  if (blockIdx.y == 0) { w = qkv_w; wt = qkvWt; N = 768; }
  else if (blockIdx.y == 1) { w = proj_w; wt = projWt; N = 256; }
  else { w = fc1_w; wt = fc1Wt; N = 1024; }
  if (idx < N * 256) {
    int n = idx >> 8, k = idx & 255;
    wt[idx] = (bf16_t)w[(size_t)k * N + n];
  }
}

__global__ void transpose_cast(const float* __restrict__ w, bf16_t* __restrict__ wt,
                               int K, int N) {
  int idx = blockIdx.x * 256 + threadIdx.x;
  if (idx < N * K) {
    int n = idx / K, k = idx - n * K;
    wt[idx] = (bf16_t)w[(size_t)k * N + n];
  }
}

// ---------------- bias+mask table: bm[type][head][64][64] fp32 -----------
__global__ void build_bm(const float* __restrict__ rpb, float* __restrict__ bm) {
  int t = blockIdx.x, h = blockIdx.y;
  int wr = (t & 2) ? 7 : 0, wc = (t & 1) ? 7 : 0;
  for (int e = threadIdx.x; e < 4096; e += 256) {
    int r = e >> 6, c = e & 63;
    float v;
    if (c >= 49) {
      v = -30000.f;
    } else if (r >= 49) {
      v = 0.f;
    } else {
      int r1 = r / 7, c1 = r - r1 * 7;
      int r2 = c / 7, c2 = c - r2 * 7;
      v = rpb[((r1 - r2 + 6) * 13 + (c1 - c2 + 6)) * 8 + h];
      int hp = wr * 7 + r1, wp = wc * 7 + c1;
      int hq = wr * 7 + r2, wq = wc * 7 + c2;
      int ri = (hp < 49 ? 0 : (hp < 53 ? 1 : 2)) * 3 + (wp < 49 ? 0 : (wp < 53 ? 1 : 2));
      int rj = (hq < 49 ? 0 : (hq < 53 ? 1 : 2)) * 3 + (wq < 49 ? 0 : (wq < 53 ? 1 : 2));
      if (ri != rj) v -= 100.f;
    }
    bm[((size_t)(t * 8 + h) * 64 + r) * 64 + c] = v;
  }
}

// ---------------- LayerNorm (+ optional shift/window gather) -> bf16 ------
__global__ __launch_bounds__(256)
void ln_cast(const float* __restrict__ src, const float* __restrict__ gamma,
             const float* __restrict__ beta, bf16_t* __restrict__ dst, int windowed) {
  int row = blockIdx.x * 4 + (threadIdx.x >> 6);
  int lane = threadIdx.x & 63;
  size_t srow;
  if (windowed) {
    int w = row / 49, t = row - w * 49;
    int img = w >> 6, wi = w & 63;
    int wr = wi >> 3, wc = wi & 7;
    int rr = t / 7, cc = t - rr * 7;
    int h = wr * 7 + rr + 3; if (h >= 56) h -= 56;
    int ww = wc * 7 + cc + 3; if (ww >= 56) ww -= 56;
    srow = (size_t)img * 3136 + h * 56 + ww;
  } else {
    srow = row;
  }
  float4 v = *(const float4*)(src + srow * 256 + lane * 4);
  float s = v.x + v.y + v.z + v.w;
  float s2 = v.x * v.x + v.y * v.y + v.z * v.z + v.w * v.w;
#pragma unroll
  for (int off = 32; off > 0; off >>= 1) {
    s += __shfl_xor(s, off);
    s2 += __shfl_xor(s2, off);
  }
  float mu = s * (1.0f / 256.0f);
  float rs = rsqrtf(s2 * (1.0f / 256.0f) - mu * mu + 1e-5f);
  float4 g = *(const float4*)(gamma + lane * 4);
  float4 b = *(const float4*)(beta + lane * 4);
  bf16x4 o;
  o[0] = (bf16_t)((v.x - mu) * rs * g.x + b.x);
  o[1] = (bf16_t)((v.y - mu) * rs * g.y + b.y);
  o[2] = (bf16_t)((v.z - mu) * rs * g.z + b.z);
  o[3] = (bf16_t)((v.w - mu) * rs * g.w + b.w);
  *(bf16x4*)(dst + (size_t)row * 256 + lane * 4) = o;
}

// ---------------- GEMM: C[M,N] = A[M,K] * Bt[N,K]^T -----------------------
// 1-D grid, n-major within m: consecutive blocks share the A-tile (L2 reuse).
// MODE 0: +bias -> bf16 (QKV)   MODE 3: +bias+Res[map(row)] -> fp32 (proj)
template <int MODE>
__global__ __launch_bounds__(256)
void gemm_bt(const bf16_t* __restrict__ A, const bf16_t* __restrict__ Bt,
             const float* __restrict__ bias,
             bf16_t* Cbf, float* Cf, const float* Res,
             int M, int N, int K, int nblk) {
  __shared__ __align__(16) bf16_t As[128 * 32];
  __shared__ __align__(16) bf16_t Bs[128 * 32];
  const int tid = threadIdx.x;
  const int lane = tid & 63;
  const int wave = tid >> 6;
  const int wm = wave & 1, wn = wave >> 1;
  const int bid = blockIdx.x;
  const int m_idx = bid / nblk;
  const int n_idx = bid - m_idx * nblk;
  const int m0 = m_idx * 128;
  const int n0 = n_idx * 128;

  f32x4 acc[4][4];
#pragma unroll
  for (int i = 0; i < 4; i++)
#pragma unroll
    for (int j = 0; j < 4; j++) acc[i][j] = f32x4{0.f, 0.f, 0.f, 0.f};

  const bf16_t* Ag = A + (size_t)m0 * K;
  const bf16_t* Bg = Bt + (size_t)n0 * K;
  const int lr = lane & 15;
  const int kq = (lane >> 4) * 8;

  for (int k0 = 0; k0 < K; k0 += 32) {
#pragma unroll
    for (int it = 0; it < 2; it++) {
      int slot = it * 256 + tid;
      int row = slot >> 2;
      int ko = (slot & 3) << 3;
      bf16_t* ldsA = As + (it * 256 + wave * 64) * 8;
      bf16_t* ldsB = Bs + (it * 256 + wave * 64) * 8;
      gload_lds16(Ag + (size_t)row * K + k0 + ko, ldsA);
      gload_lds16(Bg + (size_t)row * K + k0 + ko, ldsB);
    }
    __syncthreads();
    bf16x8 af[4], bfr[4];
#pragma unroll
    for (int i = 0; i < 4; i++) {
      af[i]  = *(const bf16x8*)(As + (wm * 64 + i * 16 + lr) * 32 + kq);
      bfr[i] = *(const bf16x8*)(Bs + (wn * 64 + i * 16 + lr) * 32 + kq);
    }
#pragma unroll
    for (int i = 0; i < 4; i++)
#pragma unroll
      for (int j = 0; j < 4; j++)
        acc[i][j] = __builtin_amdgcn_mfma_f32_16x16x32_bf16(af[i], bfr[j], acc[i][j], 0, 0, 0);
    __syncthreads();
  }

  const int quad = lane >> 4;
#pragma unroll
  for (int i = 0; i < 4; i++) {
    int rbase = m0 + wm * 64 + i * 16 + quad * 4;
#pragma unroll
    for (int j = 0; j < 4; j++) {
      int col = n0 + wn * 64 + j * 16 + lr;
      float bi = bias[col];
#pragma unroll
      for (int r = 0; r < 4; r++) {
        int row = rbase + r;
        float v = acc[i][j][r] + bi;
        if (MODE == 0) {
          Cbf[(size_t)row * N + col] = (bf16_t)v;
        } else {
          int w = row / 49, t = row - w * 49;
          int img = w >> 6, wi = w & 63;
          int wr = wi >> 3, wc = wi & 7;
          int rr = t / 7, cc = t - rr * 7;
          int h = wr * 7 + rr + 3; if (h >= 56) h -= 56;
          int ww2 = wc * 7 + cc + 3; if (ww2 >= 56) ww2 -= 56;
          size_t idx = ((size_t)img * 3136 + h * 56 + ww2) * 256 + col;
          Cf[idx] = v + Res[idx];
        }
      }
    }
  }
}

// ---------------- MFMA attention: one block (4 waves) per (window, head) --
__global__ __launch_bounds__(256)
void attn_mfma(const bf16_t* __restrict__ qkv, const float* __restrict__ bm,
               bf16_t* __restrict__ o) {
  __shared__ __align__(16) bf16_t Ps[64 * 72];
  __shared__ __align__(16) bf16_t Vt[32 * 72];
  const int w = blockIdx.x, h = blockIdx.y;
  const int tid = threadIdx.x;
  const int lane = tid & 63, wv = tid >> 6;
  const int lr = lane & 15, quad = lane >> 4;
  const int wi = w & 63;
  const int mtype = (((wi >> 3) == 7) ? 2 : 0) | (((wi & 7) == 7) ? 1 : 0);
  const bf16_t* base = qkv + (size_t)w * 49 * 768 + h * 32;

  bf16x8 zero8;
#pragma unroll
  for (int z = 0; z < 8; z++) zero8[z] = (bf16_t)0.f;

  {
    int tok = tid >> 2, d8 = (tid & 3) * 8;
    bf16x8 v8 = zero8;
    if (tok < 49) v8 = *(const bf16x8*)(base + (size_t)tok * 768 + 512 + d8);
#pragma unroll
    for (int z = 0; z < 8; z++) Vt[(d8 + z) * 72 + tok] = v8[z];
  }
  __syncthreads();

  const int mrow = 16 * wv + lr;
  bf16x8 aq = zero8;
  if (mrow < 49) aq = *(const bf16x8*)(base + (size_t)mrow * 768 + quad * 8);
  f32x4 s[4];
#pragma unroll
  for (int j = 0; j < 4; j++) {
    int nrow = 16 * j + lr;
    bf16x8 bk = zero8;
    if (nrow < 49) bk = *(const bf16x8*)(base + (size_t)nrow * 768 + 256 + quad * 8);
    s[j] = __builtin_amdgcn_mfma_f32_16x16x32_bf16(aq, bk, f32x4{0.f, 0.f, 0.f, 0.f}, 0, 0, 0);
  }

  const float* bmb = bm + ((size_t)(mtype * 8 + h) * 64 + 16 * wv) * 64;
  float inv[4];
#pragma unroll
  for (int reg = 0; reg < 4; reg++) {
    int rl = quad * 4 + reg;
    float v0[4];
    float mx = -1e30f;
#pragma unroll
    for (int j = 0; j < 4; j++) {
      float v = s[j][reg] * 0.17677669529663689f + bmb[rl * 64 + 16 * j + lr];
      v0[j] = v;
      mx = fmaxf(mx, v);
    }
#pragma unroll
    for (int off = 8; off > 0; off >>= 1) mx = fmaxf(mx, __shfl_xor(mx, off));
    float sum = 0.f;
#pragma unroll
    for (int j = 0; j < 4; j++) {
      float e = __expf(v0[j] - mx);
      v0[j] = e;
      sum += e;
    }
#pragma unroll
    for (int off = 8; off > 0; off >>= 1) sum += __shfl_xor(sum, off);
    inv[reg] = 1.0f / sum;
#pragma unroll
    for (int j = 0; j < 4; j++)
      Ps[(16 * wv + rl) * 72 + 16 * j + lr] = (bf16_t)v0[j];
  }

  f32x4 oacc[2];
  oacc[0] = f32x4{0.f, 0.f, 0.f, 0.f};
  oacc[1] = f32x4{0.f, 0.f, 0.f, 0.f};
#pragma unroll
  for (int kk = 0; kk < 2; kk++) {
    bf16x8 ap = *(const bf16x8*)(Ps + (16 * wv + lr) * 72 + kk * 32 + quad * 8);
#pragma unroll
    for (int n = 0; n < 2; n++) {
      bf16x8 bv = *(const bf16x8*)(Vt + (16 * n + lr) * 72 + kk * 32 + quad * 8);
      oacc[n] = __builtin_amdgcn_mfma_f32_16x16x32_bf16(ap, bv, oacc[n], 0, 0, 0);
    }
  }
#pragma unroll
  for (int n = 0; n < 2; n++) {
#pragma unroll
    for (int reg = 0; reg < 4; reg++) {
      int row = 16 * wv + quad * 4 + reg;
      if (row < 49) {
        int d = 16 * n + lr;
        o[((size_t)w * 49 + row) * 256 + h * 32 + d] = (bf16_t)(oacc[n][reg] * inv[reg]);
      }
    }
  }
}

// ---------------- FUSED MLP v8: out += fc2(gelu(fc1(y2))) -----------------
// 256 threads = 4 waves, 64-row M-tile (v3 per-wave math).
// 64 stages of 16 KB, Ws = 2 x 16 KB ping-pong (LDS total 49 KB -> 3
// blocks/CU, the empirically-dominant factor). Per stage:
//   __syncthreads()            // drains DMA issued LAST stage (hidden)
//   issue STAGE(s+1) -> buf^1  // 4 gload_lds/thread
//   setprio(1); 16 MFMA from buf^0; setprio(0)
// GELU sits after the B0-stage issue (overlaps its DMA latency).
// Weight layouts XOR-swizzled both-sides (verbatim v6, proven): phase A
// byte^=((row&7)<<4) on 128B rows, phase B byte^=((row&3)<<4) on 64B rows.
__global__ __launch_bounds__(256, 3)
void fused_mlp(const bf16_t* __restrict__ y2, const bf16_t* __restrict__ W1t,
               const float* __restrict__ b1, const bf16_t* __restrict__ W2t,
               const float* __restrict__ b2, float* __restrict__ out) {
  __shared__ __align__(16) bf16_t Ws[2 * 8192];     // 2 x 16 KB ping-pong
  __shared__ __align__(16) bf16_t Hs[4 * 16 * 136]; // 17 KB, per-wave strips
  const int tid = threadIdx.x;
  const int lane = tid & 63, wave = tid >> 6;
  const int lr = lane & 15, quad = lane >> 4;
  const int m0 = blockIdx.x * 64;
  bf16_t* HsW = Hs + wave * (16 * 136);

  // resident A-frags: row = m0+16*wave+lr, k = i*32 + quad*8, i in [0,8)
  const bf16_t* Arow = y2 + (size_t)(m0 + 16 * wave + lr) * 256;
  bf16x8 aFf[8];
#pragma unroll
  for (int i = 0; i < 8; i++)
    aFf[i] = *(const bf16x8*)(Arow + i * 32 + quad * 8);

  f32x4 acc2[16];
#pragma unroll
  for (int n = 0; n < 16; n++) acc2[n] = f32x4{0.f, 0.f, 0.f, 0.f};

  // staging address math (verbatim v6, correctness-proven).
  // DMA dest is linear: buf*8192 + it*2048 + wave*512 + lane*8 (elems).
  // phase A: row = it*32 + wave*8 + (lane>>3), 128B rows; source k pre-swz.
  // phase B: row = it*64 + wave*16 + (lane>>2), 64B rows; source k pre-swz.
  const int rowA = wave * 8 + (lane >> 3);
  const int koffA = ((((lane & 7) << 4) ^ (((lane >> 3) & 7) << 4)) >> 1);
  const int rowB = wave * 16 + (lane >> 2);
  const int koffB = ((((lane & 3) << 4) ^ (((lane >> 2) & 3) << 4)) >> 1);
  const int swzA = (lr & 7) << 4;  // read-side byte swizzle, row&7 = lr&7
  const int swzB = (lr & 3) << 4;  // read-side byte swizzle, row&3 = lr&3

  auto issueA = [&](int hc2, int sub2, int buf) {
    // W1 tile: rows [hc2*128, +128) x k [sub2*64, +64)
#pragma unroll
    for (int it = 0; it < 4; it++)
      gload_lds16(W1t + (size_t)(hc2 * 128 + it * 32 + rowA) * 256 + sub2 * 64 + koffA,
                  Ws + buf * 8192 + it * 2048 + wave * 512);
  };
  auto issueB = [&](int hc2, int sub2, int buf) {
    // W2 tile: rows [0, 256) x k [hc2*128 + sub2*32, +32)
#pragma unroll
    for (int it = 0; it < 4; it++)
      gload_lds16(W2t + (size_t)(it * 64 + rowB) * 1024 + hc2 * 128 + sub2 * 32 + koffB,
                  Ws + buf * 8192 + it * 2048 + wave * 512);
  };

  issueA(0, 0, 0);  // prologue: stage 0 -> buf0

  for (int hc = 0; hc < 8; hc++) {
    f32x4 acc1[8];
#pragma unroll
    for (int j = 0; j < 8; j++) acc1[j] = f32x4{0.f, 0.f, 0.f, 0.f};

    // ---- phase A: 4 stages (sub parity = buffer parity each hc)
#pragma unroll
    for (int sub = 0; sub < 4; sub++) {
      __syncthreads();                        // drains DMA(s), frees buf^1
      if (sub < 3) issueA(hc, sub + 1, (sub + 1) & 1);
      else         issueB(hc, 0, (sub + 1) & 1);
      const char* WsC = (const char*)(Ws + (sub & 1) * 8192);
      __builtin_amdgcn_s_setprio(1);
#pragma unroll
      for (int kk2 = 0; kk2 < 2; kk2++) {
        bf16x8 aa = aFf[sub * 2 + kk2];
#pragma unroll
        for (int j = 0; j < 8; j++) {
          bf16x8 b = *(const bf16x8*)(WsC + (16 * j + lr) * 128 +
                                      ((kk2 * 64 + quad * 16) ^ swzA));
          acc1[j] = __builtin_amdgcn_mfma_f32_16x16x32_bf16(aa, b, acc1[j], 0, 0, 0);
        }
      }
      __builtin_amdgcn_s_setprio(0);
      if (sub == 3) {
        // GELU (exact, erf) -> wave-local Hs; overlaps B0's in-flight DMA
#pragma unroll
        for (int j = 0; j < 8; j++) {
          float bias1 = b1[hc * 128 + 16 * j + lr];
#pragma unroll
          for (int reg = 0; reg < 4; reg++) {
            float v = acc1[j][reg] + bias1;
            v = 0.5f * v * (1.0f + erff(v * 0.70710678118654752f));
            HsW[(4 * quad + reg) * 136 + 16 * j + lr] = (bf16_t)v;
          }
        }
      }
    }

    // ---- phase B: 4 stages
#pragma unroll
    for (int sub = 0; sub < 4; sub++) {
      __syncthreads();
      if (sub < 3)      issueB(hc, sub + 1, (sub + 1) & 1);
      else if (hc < 7)  issueA(hc + 1, 0, (sub + 1) & 1);
      const char* WsC = (const char*)(Ws + (sub & 1) * 8192);
      bf16x8 ah = *(const bf16x8*)(HsW + lr * 136 + sub * 32 + quad * 8);
      __builtin_amdgcn_s_setprio(1);
#pragma unroll
      for (int n = 0; n < 16; n++) {
        bf16x8 bw = *(const bf16x8*)(WsC + (16 * n + lr) * 64 +
                                     ((quad * 16) ^ swzB));
        acc2[n] = __builtin_amdgcn_mfma_f32_16x16x32_bf16(ah, bw, acc2[n], 0, 0, 0);
      }
      __builtin_amdgcn_s_setprio(0);
    }
  }

  // epilogue: out += acc2 + b2 (rows 16*wave + 4*quad + reg, cols 16n+lr)
#pragma unroll
  for (int n = 0; n < 16; n++) {
    int col = 16 * n + lr;
    float bi = b2[col];
#pragma unroll
    for (int reg = 0; reg < 4; reg++) {
      int row = m0 + 16 * wave + 4 * quad + reg;
      size_t idx = (size_t)row * 256 + col;
      out[idx] = acc2[n][reg] + bi + out[idx];
    }
  }
}

// ---------------- launcher ------------------------------------------------
extern "C" void kernel_launch(void* const* d_in, const int* in_sizes, int n_in,
                              void* d_out, int out_size, void* d_ws, size_t ws_size,
                              hipStream_t stream) {
  const float* x      = (const float*)d_in[0];
  const float* g1     = (const float*)d_in[1];
  const float* b1     = (const float*)d_in[2];
  const float* qkv_w  = (const float*)d_in[3];
  const float* qkv_b  = (const float*)d_in[4];
  const float* proj_w = (const float*)d_in[5];
  const float* proj_b = (const float*)d_in[6];
  const float* rpb    = (const float*)d_in[7];
  const float* g2     = (const float*)d_in[8];
  const float* b2     = (const float*)d_in[9];
  const float* fc1_w  = (const float*)d_in[10];
  const float* fc1_b  = (const float*)d_in[11];
  const float* fc2_w  = (const float*)d_in[12];
  const float* fc2_b  = (const float*)d_in[13];
  float* out = (float*)d_out;
  char* ws = (char*)d_ws;

  bf16_t* xw   = (bf16_t*)ws;                  // [0,51.4M) LN1 out, later y2
  bf16_t* qkv  = (bf16_t*)(ws + 51380224);     // [51.4,205.5M)
  bf16_t* ow   = (bf16_t*)(ws + 205520896);    // [205.5,256.9M)
  bf16_t* y2   = xw;
  bf16_t* qkvWt  = (bf16_t*)(ws + 256901120);
  bf16_t* projWt = qkvWt + 768 * 256;
  bf16_t* fc1Wt  = projWt + 256 * 256;
  bf16_t* fc2Wt  = fc1Wt + 1024 * 256;         // 512 KB, time-shared with bm
  float*  bm     = (float*)fc2Wt;

  transpose_cast3<<<dim3(1024, 3), 256, 0, stream>>>(qkv_w, proj_w, fc1_w,
                                                     qkvWt, projWt, fc1Wt);
  build_bm<<<dim3(4, 8), 256, 0, stream>>>(rpb, bm);

  ln_cast<<<25088, 256, 0, stream>>>(x, g1, b1, xw, 1);
  gemm_bt<0><<<784 * 6, 256, 0, stream>>>(xw, qkvWt, qkv_b, qkv, nullptr, nullptr,
                                          100352, 768, 256, 6);
  attn_mfma<<<dim3(2048, 8), 256, 0, stream>>>(qkv, bm, ow);
  // bm dead -> transpose fc2 into its region
  transpose_cast<<<(256 * 1024 + 255) / 256, 256, 0, stream>>>(fc2_w, fc2Wt, 1024, 256);
  gemm_bt<3><<<784 * 2, 256, 0, stream>>>(ow, projWt, proj_b, nullptr, out, x,
                                          100352, 256, 256, 2);
  ln_cast<<<25088, 256, 0, stream>>>(out, g2, b2, y2, 0);
  fused_mlp<<<1568, 256, 0, stream>>>(y2, fc1Wt, fc1_b, fc2Wt, fc2_b, out);
}

// Round 7
// 770.514 us; speedup vs baseline: 1.1032x; 1.0312x over previous
//
#include <hip/hip_runtime.h>
#include <hip/hip_bf16.h>
#include <math.h>

// Swin block: LN1 -> shift+window -> QKV -> MFMA attn -> proj(+reverse+res)
//             -> LN2 -> FUSED MLP (fc1+GELU+fc2+res, h never touches HBM)
// R12: = R11 with the phase-B staging bug fixed. R11 transplanted v7's
//     8-wave staging loop (it<2, row=it*128+...) into the 4-wave kernel ->
//     W2 rows 64..127/192..255 never staged -> absmax 0.866. Correct 4-wave
//     loop: it<4, row=it*64+wave*16+(lane>>2) (= v3's proven loop).
//     Kept from R11: (a) tanh-GELU via __expf (~10 VALU ops vs erff ~25),
//     (b) GELU inside phase-B ks2=0 after the DMA issue (fills drain
//     window; Hs wave-local -> race-free), (c) T1 XCD-contiguous block
//     swizzle in gemm_bt (bijective for grids %8==0: 4704, 1568).

typedef __bf16 bf16_t;
typedef __bf16 bf16x4 __attribute__((ext_vector_type(4)));
typedef __bf16 bf16x8 __attribute__((ext_vector_type(8)));
typedef float f32x4 __attribute__((ext_vector_type(4)));

#define AS1 __attribute__((address_space(1)))
#define AS3 __attribute__((address_space(3)))

__device__ __forceinline__ void gload_lds16(const bf16_t* g, bf16_t* l) {
  __builtin_amdgcn_global_load_lds((AS1 void*)g, (AS3 void*)l, 16, 0, 0);
}

// ---------------- weight transpose + cast (3 K=256 weights in one grid) ---
__global__ void transpose_cast3(const float* __restrict__ qkv_w,
                                const float* __restrict__ proj_w,
                                const float* __restrict__ fc1_w,
                                bf16_t* __restrict__ qkvWt,
                                bf16_t* __restrict__ projWt,
                                bf16_t* __restrict__ fc1Wt) {
  int idx = blockIdx.x * 256 + threadIdx.x;
  const float* w;
  bf16_t* wt;
  int N;
  if (blockIdx.y == 0) { w = qkv_w; wt = qkvWt; N = 768; }
  else if (blockIdx.y == 1) { w = proj_w; wt = projWt; N = 256; }
  else { w = fc1_w; wt = fc1Wt; N = 1024; }
  if (idx < N * 256) {
    int n = idx >> 8, k = idx & 255;
    wt[idx] = (bf16_t)w[(size_t)k * N + n];
  }
}

__global__ void transpose_cast(const float* __restrict__ w, bf16_t* __restrict__ wt,
                               int K, int N) {
  int idx = blockIdx.x * 256 + threadIdx.x;
  if (idx < N * K) {
    int n = idx / K, k = idx - n * K;
    wt[idx] = (bf16_t)w[(size_t)k * N + n];
  }
}

// ---------------- bias+mask table: bm[type][head][64][64] fp32 -----------
__global__ void build_bm(const float* __restrict__ rpb, float* __restrict__ bm) {
  int t = blockIdx.x, h = blockIdx.y;
  int wr = (t & 2) ? 7 : 0, wc = (t & 1) ? 7 : 0;
  for (int e = threadIdx.x; e < 4096; e += 256) {
    int r = e >> 6, c = e & 63;
    float v;
    if (c >= 49) {
      v = -30000.f;
    } else if (r >= 49) {
      v = 0.f;
    } else {
      int r1 = r / 7, c1 = r - r1 * 7;
      int r2 = c / 7, c2 = c - r2 * 7;
      v = rpb[((r1 - r2 + 6) * 13 + (c1 - c2 + 6)) * 8 + h];
      int hp = wr * 7 + r1, wp = wc * 7 + c1;
      int hq = wr * 7 + r2, wq = wc * 7 + c2;
      int ri = (hp < 49 ? 0 : (hp < 53 ? 1 : 2)) * 3 + (wp < 49 ? 0 : (wp < 53 ? 1 : 2));
      int rj = (hq < 49 ? 0 : (hq < 53 ? 1 : 2)) * 3 + (wq < 49 ? 0 : (wq < 53 ? 1 : 2));
      if (ri != rj) v -= 100.f;
    }
    bm[((size_t)(t * 8 + h) * 64 + r) * 64 + c] = v;
  }
}

// ---------------- LayerNorm (+ optional shift/window gather) -> bf16 ------
__global__ __launch_bounds__(256)
void ln_cast(const float* __restrict__ src, const float* __restrict__ gamma,
             const float* __restrict__ beta, bf16_t* __restrict__ dst, int windowed) {
  int row = blockIdx.x * 4 + (threadIdx.x >> 6);
  int lane = threadIdx.x & 63;
  size_t srow;
  if (windowed) {
    int w = row / 49, t = row - w * 49;
    int img = w >> 6, wi = w & 63;
    int wr = wi >> 3, wc = wi & 7;
    int rr = t / 7, cc = t - rr * 7;
    int h = wr * 7 + rr + 3; if (h >= 56) h -= 56;
    int ww = wc * 7 + cc + 3; if (ww >= 56) ww -= 56;
    srow = (size_t)img * 3136 + h * 56 + ww;
  } else {
    srow = row;
  }
  float4 v = *(const float4*)(src + srow * 256 + lane * 4);
  float s = v.x + v.y + v.z + v.w;
  float s2 = v.x * v.x + v.y * v.y + v.z * v.z + v.w * v.w;
#pragma unroll
  for (int off = 32; off > 0; off >>= 1) {
    s += __shfl_xor(s, off);
    s2 += __shfl_xor(s2, off);
  }
  float mu = s * (1.0f / 256.0f);
  float rs = rsqrtf(s2 * (1.0f / 256.0f) - mu * mu + 1e-5f);
  float4 g = *(const float4*)(gamma + lane * 4);
  float4 b = *(const float4*)(beta + lane * 4);
  bf16x4 o;
  o[0] = (bf16_t)((v.x - mu) * rs * g.x + b.x);
  o[1] = (bf16_t)((v.y - mu) * rs * g.y + b.y);
  o[2] = (bf16_t)((v.z - mu) * rs * g.z + b.z);
  o[3] = (bf16_t)((v.w - mu) * rs * g.w + b.w);
  *(bf16x4*)(dst + (size_t)row * 256 + lane * 4) = o;
}

// ---------------- GEMM: C[M,N] = A[M,K] * Bt[N,K]^T -----------------------
// 1-D grid, n-major within m: consecutive tiles share the A-panel. T1 XCD
// swizzle: block b computes tile (b&7)*(nwg/8)+(b>>3), giving each XCD a
// contiguous n-major tile range -> A-panel stays hot in its private L2.
// Requires gridDim.x % 8 == 0 (4704, 1568 ok).
// MODE 0: +bias -> bf16 (QKV)   MODE 3: +bias+Res[map(row)] -> fp32 (proj)
template <int MODE>
__global__ __launch_bounds__(256)
void gemm_bt(const bf16_t* __restrict__ A, const bf16_t* __restrict__ Bt,
             const float* __restrict__ bias,
             bf16_t* Cbf, float* Cf, const float* Res,
             int M, int N, int K, int nblk) {
  __shared__ __align__(16) bf16_t As[128 * 32];
  __shared__ __align__(16) bf16_t Bs[128 * 32];
  const int tid = threadIdx.x;
  const int lane = tid & 63;
  const int wave = tid >> 6;
  const int wm = wave & 1, wn = wave >> 1;
  const int bid = blockIdx.x;
  const int nwg = gridDim.x;
  const int bs = (bid & 7) * (nwg >> 3) + (bid >> 3);  // XCD-contig remap
  const int m_idx = bs / nblk;
  const int n_idx = bs - m_idx * nblk;
  const int m0 = m_idx * 128;
  const int n0 = n_idx * 128;

  f32x4 acc[4][4];
#pragma unroll
  for (int i = 0; i < 4; i++)
#pragma unroll
    for (int j = 0; j < 4; j++) acc[i][j] = f32x4{0.f, 0.f, 0.f, 0.f};

  const bf16_t* Ag = A + (size_t)m0 * K;
  const bf16_t* Bg = Bt + (size_t)n0 * K;
  const int lr = lane & 15;
  const int kq = (lane >> 4) * 8;

  for (int k0 = 0; k0 < K; k0 += 32) {
#pragma unroll
    for (int it = 0; it < 2; it++) {
      int slot = it * 256 + tid;
      int row = slot >> 2;
      int ko = (slot & 3) << 3;
      bf16_t* ldsA = As + (it * 256 + wave * 64) * 8;
      bf16_t* ldsB = Bs + (it * 256 + wave * 64) * 8;
      gload_lds16(Ag + (size_t)row * K + k0 + ko, ldsA);
      gload_lds16(Bg + (size_t)row * K + k0 + ko, ldsB);
    }
    __syncthreads();
    bf16x8 af[4], bfr[4];
#pragma unroll
    for (int i = 0; i < 4; i++) {
      af[i]  = *(const bf16x8*)(As + (wm * 64 + i * 16 + lr) * 32 + kq);
      bfr[i] = *(const bf16x8*)(Bs + (wn * 64 + i * 16 + lr) * 32 + kq);
    }
#pragma unroll
    for (int i = 0; i < 4; i++)
#pragma unroll
      for (int j = 0; j < 4; j++)
        acc[i][j] = __builtin_amdgcn_mfma_f32_16x16x32_bf16(af[i], bfr[j], acc[i][j], 0, 0, 0);
    __syncthreads();
  }

  const int quad = lane >> 4;
#pragma unroll
  for (int i = 0; i < 4; i++) {
    int rbase = m0 + wm * 64 + i * 16 + quad * 4;
#pragma unroll
    for (int j = 0; j < 4; j++) {
      int col = n0 + wn * 64 + j * 16 + lr;
      float bi = bias[col];
#pragma unroll
      for (int r = 0; r < 4; r++) {
        int row = rbase + r;
        float v = acc[i][j][r] + bi;
        if (MODE == 0) {
          Cbf[(size_t)row * N + col] = (bf16_t)v;
        } else {
          int w = row / 49, t = row - w * 49;
          int img = w >> 6, wi = w & 63;
          int wr = wi >> 3, wc = wi & 7;
          int rr = t / 7, cc = t - rr * 7;
          int h = wr * 7 + rr + 3; if (h >= 56) h -= 56;
          int ww2 = wc * 7 + cc + 3; if (ww2 >= 56) ww2 -= 56;
          size_t idx = ((size_t)img * 3136 + h * 56 + ww2) * 256 + col;
          Cf[idx] = v + Res[idx];
        }
      }
    }
  }
}

// ---------------- MFMA attention: one block (4 waves) per (window, head) --
__global__ __launch_bounds__(256)
void attn_mfma(const bf16_t* __restrict__ qkv, const float* __restrict__ bm,
               bf16_t* __restrict__ o) {
  __shared__ __align__(16) bf16_t Ps[64 * 72];
  __shared__ __align__(16) bf16_t Vt[32 * 72];
  const int w = blockIdx.x, h = blockIdx.y;
  const int tid = threadIdx.x;
  const int lane = tid & 63, wv = tid >> 6;
  const int lr = lane & 15, quad = lane >> 4;
  const int wi = w & 63;
  const int mtype = (((wi >> 3) == 7) ? 2 : 0) | (((wi & 7) == 7) ? 1 : 0);
  const bf16_t* base = qkv + (size_t)w * 49 * 768 + h * 32;

  bf16x8 zero8;
#pragma unroll
  for (int z = 0; z < 8; z++) zero8[z] = (bf16_t)0.f;

  {
    int tok = tid >> 2, d8 = (tid & 3) * 8;
    bf16x8 v8 = zero8;
    if (tok < 49) v8 = *(const bf16x8*)(base + (size_t)tok * 768 + 512 + d8);
#pragma unroll
    for (int z = 0; z < 8; z++) Vt[(d8 + z) * 72 + tok] = v8[z];
  }
  __syncthreads();

  const int mrow = 16 * wv + lr;
  bf16x8 aq = zero8;
  if (mrow < 49) aq = *(const bf16x8*)(base + (size_t)mrow * 768 + quad * 8);
  f32x4 s[4];
#pragma unroll
  for (int j = 0; j < 4; j++) {
    int nrow = 16 * j + lr;
    bf16x8 bk = zero8;
    if (nrow < 49) bk = *(const bf16x8*)(base + (size_t)nrow * 768 + 256 + quad * 8);
    s[j] = __builtin_amdgcn_mfma_f32_16x16x32_bf16(aq, bk, f32x4{0.f, 0.f, 0.f, 0.f}, 0, 0, 0);
  }

  const float* bmb = bm + ((size_t)(mtype * 8 + h) * 64 + 16 * wv) * 64;
  float inv[4];
#pragma unroll
  for (int reg = 0; reg < 4; reg++) {
    int rl = quad * 4 + reg;
    float v0[4];
    float mx = -1e30f;
#pragma unroll
    for (int j = 0; j < 4; j++) {
      float v = s[j][reg] * 0.17677669529663689f + bmb[rl * 64 + 16 * j + lr];
      v0[j] = v;
      mx = fmaxf(mx, v);
    }
#pragma unroll
    for (int off = 8; off > 0; off >>= 1) mx = fmaxf(mx, __shfl_xor(mx, off));
    float sum = 0.f;
#pragma unroll
    for (int j = 0; j < 4; j++) {
      float e = __expf(v0[j] - mx);
      v0[j] = e;
      sum += e;
    }
#pragma unroll
    for (int off = 8; off > 0; off >>= 1) sum += __shfl_xor(sum, off);
    inv[reg] = 1.0f / sum;
#pragma unroll
    for (int j = 0; j < 4; j++)
      Ps[(16 * wv + rl) * 72 + 16 * j + lr] = (bf16_t)v0[j];
  }

  f32x4 oacc[2];
  oacc[0] = f32x4{0.f, 0.f, 0.f, 0.f};
  oacc[1] = f32x4{0.f, 0.f, 0.f, 0.f};
#pragma unroll
  for (int kk = 0; kk < 2; kk++) {
    bf16x8 ap = *(const bf16x8*)(Ps + (16 * wv + lr) * 72 + kk * 32 + quad * 8);
#pragma unroll
    for (int n = 0; n < 2; n++) {
      bf16x8 bv = *(const bf16x8*)(Vt + (16 * n + lr) * 72 + kk * 32 + quad * 8);
      oacc[n] = __builtin_amdgcn_mfma_f32_16x16x32_bf16(ap, bv, oacc[n], 0, 0, 0);
    }
  }
#pragma unroll
  for (int n = 0; n < 2; n++) {
#pragma unroll
    for (int reg = 0; reg < 4; reg++) {
      int row = 16 * wv + quad * 4 + reg;
      if (row < 49) {
        int d = 16 * n + lr;
        o[((size_t)w * 49 + row) * 256 + h * 32 + d] = (bf16_t)(oacc[n][reg] * inv[reg]);
      }
    }
  }
}

// ---------------- FUSED MLP v10: out += fc2(gelu(fc1(y2))) ----------------
// = v3 (268us champion: 4 waves, 64-row tile, serial stage/sync, 49KB LDS,
// 3 blocks/CU) + (a) tanh-GELU (one __expf) + (b) GELU inside phase-B
// ks2=0 after the DMA issue (fills the drain window; Hs wave-local).
// Phase-B staging is v3's proven 4-wave loop: it<4, row=it*64+wave*16+...
__global__ __launch_bounds__(256, 3)
void fused_mlp(const bf16_t* __restrict__ y2, const bf16_t* __restrict__ W1t,
               const float* __restrict__ b1, const bf16_t* __restrict__ W2t,
               const float* __restrict__ b2, float* __restrict__ out) {
  __shared__ __align__(16) bf16_t Ws[16384];        // 32 KB weight staging
  __shared__ __align__(16) bf16_t Hs[4 * 16 * 136]; // 17 KB, per-wave strips
  const int tid = threadIdx.x;
  const int lane = tid & 63, wave = tid >> 6;
  const int lr = lane & 15, quad = lane >> 4;
  const int m0 = blockIdx.x * 64;
  bf16_t* HsW = Hs + wave * (16 * 136);

  // resident A-frags: row = m0+16*wave+lr, k = ks*128 + kk*32 + quad*8
  const bf16_t* Arow = y2 + (size_t)(m0 + 16 * wave + lr) * 256;
  bf16x8 aF[2][4];
#pragma unroll
  for (int ks = 0; ks < 2; ks++)
#pragma unroll
    for (int kk = 0; kk < 4; kk++)
      aF[ks][kk] = *(const bf16x8*)(Arow + ks * 128 + kk * 32 + quad * 8);

  f32x4 acc2[16];
#pragma unroll
  for (int n = 0; n < 16; n++) acc2[n] = f32x4{0.f, 0.f, 0.f, 0.f};

  for (int hc = 0; hc < 8; hc++) {
    // ---- phase A: H[16w..+16, 128] = y2 @ W1t[hc*128..+128]^T
    f32x4 acc1[8];
#pragma unroll
    for (int j = 0; j < 8; j++) acc1[j] = f32x4{0.f, 0.f, 0.f, 0.f};

    for (int ks = 0; ks < 2; ks++) {
      __syncthreads();                       // all waves done reading Ws
#pragma unroll
      for (int kk = 0; kk < 4; kk++) {       // stage 128 rows x 32 k (8KB/kk)
#pragma unroll
        for (int it = 0; it < 2; it++) {
          int row = it * 64 + wave * 16 + (lane >> 2);
          int k8 = lane & 3;
          const bf16_t* src = W1t + (size_t)(hc * 128 + row) * 256
                              + ks * 128 + kk * 32 + k8 * 8;
          gload_lds16(src, Ws + kk * 4096 + (it * 64 + wave * 16) * 32);
        }
      }
      __syncthreads();                       // staged data visible
#pragma unroll
      for (int kk = 0; kk < 4; kk++) {
#pragma unroll
        for (int j = 0; j < 8; j++) {
          bf16x8 b = *(const bf16x8*)(Ws + kk * 4096 + (16 * j + lr) * 32 + quad * 8);
          acc1[j] = __builtin_amdgcn_mfma_f32_16x16x32_bf16(aF[ks][kk], b, acc1[j], 0, 0, 0);
        }
      }
    }
    // ---- phase B: acc2 += H @ W2t[:, hc*128..+128]^T
    for (int ks2 = 0; ks2 < 2; ks2++) {
      __syncthreads();                       // Ws reads done (Hs is wave-local)
#pragma unroll
      for (int kk = 0; kk < 2; kk++) {       // stage 256 rows x 32 k (16KB/kk)
#pragma unroll
        for (int it = 0; it < 4; it++) {     // 4 waves x 4 its x 16 rows = 256
          int row = it * 64 + wave * 16 + (lane >> 2);
          int k8 = lane & 3;
          const bf16_t* src = W2t + (size_t)row * 1024
                              + hc * 128 + ks2 * 64 + kk * 32 + k8 * 8;
          gload_lds16(src, Ws + kk * 8192 + (it * 64 + wave * 16) * 32);
        }
      }
      if (ks2 == 0) {
        // GELU (tanh form) -> wave-local Hs strip; overlaps the in-flight
        // weight DMA issued just above. gelu(v) ~= v*sigmoid(2u),
        // u = sqrt(2/pi)*(v + 0.044715 v^3); computed as v - v/(e^{2u}+1)
        // (overflow-safe: e=inf -> v; e=0 -> 0).
#pragma unroll
        for (int j = 0; j < 8; j++) {
          float bias1 = b1[hc * 128 + 16 * j + lr];
#pragma unroll
          for (int reg = 0; reg < 4; reg++) {
            float v = acc1[j][reg] + bias1;
            float u2 = v * (1.5957691216057308f + 0.0713548162726228f * v * v);
            float e = __expf(u2);
            v = v - v / (e + 1.0f);
            HsW[(4 * quad + reg) * 136 + 16 * j + lr] = (bf16_t)v;
          }
        }
      }
      __syncthreads();
#pragma unroll
      for (int kk = 0; kk < 2; kk++) {
        bf16x8 ah = *(const bf16x8*)(HsW + lr * 136 + ks2 * 64 + kk * 32 + quad * 8);
#pragma unroll
        for (int n = 0; n < 16; n++) {
          bf16x8 bw = *(const bf16x8*)(Ws + kk * 8192 + (16 * n + lr) * 32 + quad * 8);
          acc2[n] = __builtin_amdgcn_mfma_f32_16x16x32_bf16(ah, bw, acc2[n], 0, 0, 0);
        }
      }
    }
  }

  // epilogue: out += acc2 + b2 (rows 16*wave + 4*quad + reg, cols 16n+lr)
#pragma unroll
  for (int n = 0; n < 16; n++) {
    int col = 16 * n + lr;
    float bi = b2[col];
#pragma unroll
    for (int reg = 0; reg < 4; reg++) {
      int row = m0 + 16 * wave + 4 * quad + reg;
      size_t idx = (size_t)row * 256 + col;
      out[idx] = acc2[n][reg] + bi + out[idx];
    }
  }
}

// ---------------- launcher ------------------------------------------------
extern "C" void kernel_launch(void* const* d_in, const int* in_sizes, int n_in,
                              void* d_out, int out_size, void* d_ws, size_t ws_size,
                              hipStream_t stream) {
  const float* x      = (const float*)d_in[0];
  const float* g1     = (const float*)d_in[1];
  const float* b1     = (const float*)d_in[2];
  const float* qkv_w  = (const float*)d_in[3];
  const float* qkv_b  = (const float*)d_in[4];
  const float* proj_w = (const float*)d_in[5];
  const float* proj_b = (const float*)d_in[6];
  const float* rpb    = (const float*)d_in[7];
  const float* g2     = (const float*)d_in[8];
  const float* b2     = (const float*)d_in[9];
  const float* fc1_w  = (const float*)d_in[10];
  const float* fc1_b  = (const float*)d_in[11];
  const float* fc2_w  = (const float*)d_in[12];
  const float* fc2_b  = (const float*)d_in[13];
  float* out = (float*)d_out;
  char* ws = (char*)d_ws;

  bf16_t* xw   = (bf16_t*)ws;                  // [0,51.4M) LN1 out, later y2
  bf16_t* qkv  = (bf16_t*)(ws + 51380224);     // [51.4,205.5M)
  bf16_t* ow   = (bf16_t*)(ws + 205520896);    // [205.5,256.9M)
  bf16_t* y2   = xw;
  bf16_t* qkvWt  = (bf16_t*)(ws + 256901120);
  bf16_t* projWt = qkvWt + 768 * 256;
  bf16_t* fc1Wt  = projWt + 256 * 256;
  bf16_t* fc2Wt  = fc1Wt + 1024 * 256;         // 512 KB, time-shared with bm
  float*  bm     = (float*)fc2Wt;

  transpose_cast3<<<dim3(1024, 3), 256, 0, stream>>>(qkv_w, proj_w, fc1_w,
                                                     qkvWt, projWt, fc1Wt);
  build_bm<<<dim3(4, 8), 256, 0, stream>>>(rpb, bm);

  ln_cast<<<25088, 256, 0, stream>>>(x, g1, b1, xw, 1);
  gemm_bt<0><<<784 * 6, 256, 0, stream>>>(xw, qkvWt, qkv_b, qkv, nullptr, nullptr,
                                          100352, 768, 256, 6);
  attn_mfma<<<dim3(2048, 8), 256, 0, stream>>>(qkv, bm, ow);
  // bm dead -> transpose fc2 into its region
  transpose_cast<<<(256 * 1024 + 255) / 256, 256, 0, stream>>>(fc2_w, fc2Wt, 1024, 256);
  gemm_bt<3><<<784 * 2, 256, 0, stream>>>(ow, projWt, proj_b, nullptr, out, x,
                                          100352, 256, 256, 2);
  ln_cast<<<25088, 256, 0, stream>>>(out, g2, b2, y2, 0);
  fused_mlp<<<1568, 256, 0, stream>>>(y2, fc1Wt, fc1_b, fc2Wt, fc2_b, out);
}